// Round 6
// baseline (447.695 us; speedup 1.0000x reference)
//
#include <hip/hip_runtime.h>
#include <hip/hip_bf16.h>

using u16 = unsigned short;
typedef __attribute__((ext_vector_type(4))) float f32x4;
typedef __attribute__((ext_vector_type(8))) _Float16 f16x8;
typedef __attribute__((ext_vector_type(4))) unsigned short u16x4;

#define MFMA(a,b,c) __builtin_amdgcn_mfma_f32_16x16x32_f16((a),(b),(c),0,0,0)

__device__ __forceinline__ u16 f2h(float f){
  _Float16 h = (_Float16)f;
  return __builtin_bit_cast(u16, h);
}
__device__ __forceinline__ float sigm(float x){
  return 1.f / (1.f + __expf(-x));
}
// load 8 consecutive fp32 weights W[row][koff..koff+7], convert to f16x8 fragment
__device__ __forceinline__ f16x8 ldw8(const float* __restrict__ W, int row, int koff){
  const float4* p = (const float4*)(W + row * 128 + koff);
  float4 f0 = p[0], f1 = p[1];
  f16x8 h;
  h[0] = (_Float16)f0.x; h[1] = (_Float16)f0.y; h[2] = (_Float16)f0.z; h[3] = (_Float16)f0.w;
  h[4] = (_Float16)f1.x; h[5] = (_Float16)f1.y; h[6] = (_Float16)f1.z; h[7] = (_Float16)f1.w;
  return h;
}

// ---------------- K1: LN1 + x@[Wproj|Wgate]^T + mask*sigmoid pairing ----------------
// Tile = 128 tokens in a COLUMN of the token matrix: t1 in [k0,k0+128), t2 = j fixed.
// Writes a_r[c][t2][t1], b_r[c][t2][t1] (K-contiguous for K2, coalesced via LDS staging).
__launch_bounds__(256, 3)
__global__ void k1_ln_proj(const float* __restrict__ pair, const float* __restrict__ mask,
                           const float* __restrict__ ln1w, const float* __restrict__ ln1b,
                           const float* __restrict__ Wp, const float* __restrict__ Wg,
                           u16* __restrict__ a_r, u16* __restrict__ b_r){
  __shared__ float red_s[128], red_q[128], msk[128];
  __shared__ u16 xs[128 * 136];              // LN1 output fp16, padded stride 136
  __shared__ u16 sbuf[4][16 * 132];          // per-wave a/b staging
  int tid = threadIdx.x;
  int bid = blockIdx.x;
  int j   = bid >> 2;
  int k0  = (bid & 3) << 7;

  // Phase A: load 128x128 fp32 tile (coalesced), per-token LN stats via 32-lane shuffles
  int cpos = tid & 31;                       // float4 slot within a token row
  int rsub = tid >> 5;                       // 0..7
  float4 v[16];
  #pragma unroll
  for (int it = 0; it < 16; ++it){
    int kk = it * 8 + rsub;
    const float4* p = (const float4*)(pair + (((size_t)(k0 + kk) * 512 + j) << 7));
    v[it] = p[cpos];
    float s = v[it].x + v[it].y + v[it].z + v[it].w;
    float q = v[it].x*v[it].x + v[it].y*v[it].y + v[it].z*v[it].z + v[it].w*v[it].w;
    #pragma unroll
    for (int m = 16; m >= 1; m >>= 1){
      s += __shfl_xor(s, m);
      q += __shfl_xor(q, m);
    }
    if (cpos == 0){ red_s[kk] = s; red_q[kk] = q; }
  }
  if (tid < 128) msk[tid] = mask[(size_t)(k0 + tid) * 512 + j];
  __syncthreads();

  float4 w4 = ((const float4*)ln1w)[cpos];
  float4 b4 = ((const float4*)ln1b)[cpos];
  #pragma unroll
  for (int it = 0; it < 16; ++it){
    int kk = it * 8 + rsub;
    float mu = red_s[kk] * (1.f / 128.f);
    float var = red_q[kk] * (1.f / 128.f) - mu * mu;
    float rs = rsqrtf(var + 1e-5f);
    u16x4 o;
    o[0] = f2h((v[it].x - mu) * rs * w4.x + b4.x);
    o[1] = f2h((v[it].y - mu) * rs * w4.y + b4.y);
    o[2] = f2h((v[it].z - mu) * rs * w4.z + b4.z);
    o[3] = f2h((v[it].w - mu) * rs * w4.w + b4.w);
    *(u16x4*)&xs[kk * 136 + cpos * 4] = o;
  }
  __syncthreads();

  // Phase B: MFMA. M=128 (tokens), K=128, N=512 (proj 0..255 | gate 256..511)
  int lane = tid & 63;
  int wv   = tid >> 6;
  int l15  = lane & 15;
  int l4   = lane >> 4;
  u16* sb  = sbuf[wv];

  // paired proj/gate n-tiles: wave handles tp = pi*4+wv
  #pragma unroll
  for (int pi = 0; pi < 4; ++pi){
    int tp = pi * 4 + wv;                    // 0..15
    int nP = tp * 16 + l15;                  // proj column 0..255
    f32x4 accP[8] = {}; f32x4 accG[8] = {};
    #pragma unroll
    for (int ks = 0; ks < 4; ++ks){
      f16x8 bP = ldw8(Wp, nP, ks * 32 + l4 * 8);
      f16x8 bG = ldw8(Wg, nP, ks * 32 + l4 * 8);
      #pragma unroll
      for (int mi = 0; mi < 8; ++mi){
        f16x8 af = *(const f16x8*)&xs[(mi * 16 + l15) * 136 + ks * 32 + l4 * 8];
        accP[mi] = MFMA(af, bP, accP[mi]);
        accG[mi] = MFMA(af, bG, accG[mi]);
      }
    }
    // epilogue -> wave-private LDS staging tile [nP-local 16][token 128]
    #pragma unroll
    for (int mi = 0; mi < 8; ++mi){
      int m0 = mi * 16 + l4 * 4;
      u16x4 o;
      #pragma unroll
      for (int r = 0; r < 4; ++r){
        float p = accP[mi][r] * msk[m0 + r] * sigm(accG[mi][r]);
        o[r] = f2h(p);
      }
      *(u16x4*)&sb[l15 * 132 + m0] = o;
    }
    // flush: 8 fully-coalesced store instructions (2 rows of 256B each)
    #pragma unroll
    for (int r2 = 0; r2 < 8; ++r2){
      int row = r2 * 2 + (lane >> 5);        // 0..15
      int col = (lane & 31) * 4;             // u16 index 0..124
      u16x4 vv = *(const u16x4*)&sb[row * 132 + col];
      int nP2 = tp * 16 + row;
      int c = nP2 >> 1;
      u16* dst = (nP2 & 1) ? b_r : a_r;
      *(u16x4*)&dst[((size_t)c * 512 + j) * 512 + k0 + col] = vv;
    }
  }
}

// ---------------- K2: triangle einsum, 128 per-channel 512x512x512 fp16 GEMMs ----------------
// o_f[c][i][j] = sum_k b_r[c][i][k] * a_r[c][j][k]  (NT GEMM, direct global frag loads)
// fp32 output (no quantization of the einsum result).
// XCD-chunked swizzle: xcd = bid%8 serves channels [xcd*16, xcd*16+16) -> L2-resident.
__launch_bounds__(256, 2)
__global__ void k2_tri(const u16* __restrict__ a_r, const u16* __restrict__ b_r,
                       float* __restrict__ o_f){
  int tid = threadIdx.x;
  int p = blockIdx.x;
  int lb = (p & 7) * 256 + (p >> 3);         // bijective: 2048 = 8 * 256
  int c  = lb >> 4;
  int t  = lb & 15;
  int lane = tid & 63, wv = tid >> 6;
  int i0 = (t >> 2) * 128 + (wv >> 1) * 64;
  int j0 = (t & 3) * 128 + (wv & 1) * 64;
  int l15 = lane & 15, l4 = lane >> 4;
  const u16* pa = a_r + (size_t)c * 262144;
  const u16* pb = b_r + (size_t)c * 262144;

  f32x4 acc[4][4] = {};
  for (int ks = 0; ks < 16; ++ks){
    f16x8 A[4], B[4];
    #pragma unroll
    for (int ai = 0; ai < 4; ++ai)
      A[ai] = *(const f16x8*)&pb[(i0 + ai * 16 + l15) * 512 + ks * 32 + l4 * 8];
    #pragma unroll
    for (int bj = 0; bj < 4; ++bj)
      B[bj] = *(const f16x8*)&pa[(j0 + bj * 16 + l15) * 512 + ks * 32 + l4 * 8];
    #pragma unroll
    for (int ai = 0; ai < 4; ++ai)
      #pragma unroll
      for (int bj = 0; bj < 4; ++bj)
        acc[ai][bj] = MFMA(A[ai], B[bj], acc[ai][bj]);
  }
  float* po = o_f + (size_t)c * 262144;
  #pragma unroll
  for (int ai = 0; ai < 4; ++ai){
    #pragma unroll
    for (int r = 0; r < 4; ++r){
      int i = i0 + ai * 16 + l4 * 4 + r;
      #pragma unroll
      for (int bj = 0; bj < 4; ++bj)
        po[i * 512 + j0 + bj * 16 + l15] = acc[ai][bj][r];
    }
  }
}

// ---------------- K3: LN2 + @W_out^T, fused glin gate (LN1 recompute + @W_glin^T) ----------------
__launch_bounds__(256, 2)
__global__ void k3_out(const float* __restrict__ o_f, const float* __restrict__ pair,
                       const float* __restrict__ ln1w, const float* __restrict__ ln1b,
                       const float* __restrict__ ln2w, const float* __restrict__ ln2b,
                       const float* __restrict__ Wgl, const float* __restrict__ Wo,
                       float* __restrict__ out){
  __shared__ float ot[128 * 68];             // o_f gather tile [cin][jj], stride 68
  __shared__ u16 x1[64 * 136];               // LN1(pair) fp16 [jj][cin]
  __shared__ u16 x2[64 * 136];               // LN2(o)  fp16 [jj][cin]
  __shared__ float r1s[64], r1q[64];
  int tid = threadIdx.x, bid = blockIdx.x;
  int i  = bid >> 3;                         // output row index
  int j0 = (bid & 7) << 6;                   // 64-token j block

  // Phase A: LN1 over pair rows (i, j0+jj) -- register loads + 32-lane shuffle stats
  int cq = tid & 31, jsub = tid >> 5;        // 8 tokens per thread over 8 iters
  float4 pv[8];
  #pragma unroll
  for (int it = 0; it < 8; ++it){
    int jj = it * 8 + jsub;
    const float4* p = (const float4*)(pair + (((size_t)i * 512 + j0 + jj) << 7));
    pv[it] = p[cq];
    float s = pv[it].x + pv[it].y + pv[it].z + pv[it].w;
    float q = pv[it].x*pv[it].x + pv[it].y*pv[it].y + pv[it].z*pv[it].z + pv[it].w*pv[it].w;
    #pragma unroll
    for (int m = 16; m >= 1; m >>= 1){
      s += __shfl_xor(s, m);
      q += __shfl_xor(q, m);
    }
    if (cq == 0){ r1s[jj] = s; r1q[jj] = q; }
  }
  __syncthreads();
  {
    float4 w1 = ((const float4*)ln1w)[cq];
    float4 b1 = ((const float4*)ln1b)[cq];
    #pragma unroll
    for (int it = 0; it < 8; ++it){
      int jj = it * 8 + jsub;
      float mu = r1s[jj] * (1.f / 128.f);
      float var = r1q[jj] * (1.f / 128.f) - mu * mu;
      float rs = rsqrtf(var + 1e-5f);
      u16x4 o;
      o[0] = f2h((pv[it].x - mu) * rs * w1.x + b1.x);
      o[1] = f2h((pv[it].y - mu) * rs * w1.y + b1.y);
      o[2] = f2h((pv[it].z - mu) * rs * w1.z + b1.z);
      o[3] = f2h((pv[it].w - mu) * rs * w1.w + b1.w);
      *(u16x4*)&x1[jj * 136 + cq * 4] = o;
    }
  }

  // Phase B: gather o_f (fp32) -> ot[cin][jj]
  #pragma unroll
  for (int it = 0; it < 8; ++it){
    int f = it * 256 + tid;
    int cin = f >> 4, part = f & 15;
    float4 vld = *(const float4*)&o_f[(size_t)cin * 262144 + (size_t)i * 512 + j0 + part * 4];
    *(float4*)&ot[cin * 68 + part * 4] = vld;
  }
  __syncthreads();

  // LN2 from exact fp32 values: 4 threads per token (32 channels each)
  int jj2 = tid >> 2, qr = tid & 3;
  float s2 = 0.f, q2 = 0.f;
  #pragma unroll
  for (int u = 0; u < 32; ++u){
    float x = ot[(qr * 32 + u) * 68 + jj2];
    s2 += x; q2 += x * x;
  }
  s2 += __shfl_xor(s2, 1); q2 += __shfl_xor(q2, 1);
  s2 += __shfl_xor(s2, 2); q2 += __shfl_xor(q2, 2);
  float mu2 = s2 * (1.f / 128.f);
  float rs2 = rsqrtf(q2 * (1.f / 128.f) - mu2 * mu2 + 1e-5f);
  #pragma unroll
  for (int u = 0; u < 32; ++u){
    int cin = qr * 32 + u;
    float x = ot[cin * 68 + jj2];
    x2[jj2 * 136 + cin] = f2h((x - mu2) * rs2 * ln2w[cin] + ln2b[cin]);
  }
  __syncthreads();

  // Dual GEMM: 64 tokens x 128 cout x 128 cin (out via Wo, gate via Wgl)
  int lane = tid & 63, wv = tid >> 6;
  int l15 = lane & 15, l4 = lane >> 4;
  int n0 = wv * 32;
  f32x4 accO[4][2] = {};
  f32x4 accG[4][2] = {};
  #pragma unroll
  for (int ks = 0; ks < 4; ++ks){
    int koff = ks * 32 + l4 * 8;
    f16x8 B0 = ldw8(Wo, n0 + l15, koff);
    f16x8 B1 = ldw8(Wo, n0 + 16 + l15, koff);
    f16x8 G0 = ldw8(Wgl, n0 + l15, koff);
    f16x8 G1 = ldw8(Wgl, n0 + 16 + l15, koff);
    #pragma unroll
    for (int mi = 0; mi < 4; ++mi){
      f16x8 A2 = *(const f16x8*)&x2[(mi * 16 + l15) * 136 + koff];
      f16x8 A1 = *(const f16x8*)&x1[(mi * 16 + l15) * 136 + koff];
      accO[mi][0] = MFMA(A2, B0, accO[mi][0]);
      accO[mi][1] = MFMA(A2, B1, accO[mi][1]);
      accG[mi][0] = MFMA(A1, G0, accG[mi][0]);
      accG[mi][1] = MFMA(A1, G1, accG[mi][1]);
    }
  }
  #pragma unroll
  for (int mi = 0; mi < 4; ++mi){
    #pragma unroll
    for (int r = 0; r < 4; ++r){
      int m = mi * 16 + l4 * 4 + r;
      size_t tok = (size_t)i * 512 + j0 + m;
      #pragma unroll
      for (int nj = 0; nj < 2; ++nj){
        int cout = n0 + nj * 16 + l15;
        out[tok * 128 + cout] = accO[mi][nj][r] * sigm(accG[mi][nj][r]);
      }
    }
  }
}

extern "C" void kernel_launch(void* const* d_in, const int* in_sizes, int n_in,
                              void* d_out, int out_size, void* d_ws, size_t ws_size,
                              hipStream_t stream){
  (void)in_sizes; (void)n_in; (void)out_size; (void)ws_size;
  const float* pair = (const float*)d_in[0];
  const float* mask = (const float*)d_in[1];
  const float* ln1w = (const float*)d_in[2];
  const float* ln1b = (const float*)d_in[3];
  const float* ln2w = (const float*)d_in[4];
  const float* ln2b = (const float*)d_in[5];
  const float* Wp   = (const float*)d_in[6];
  const float* Wg   = (const float*)d_in[7];
  const float* Wo   = (const float*)d_in[8];   // W_out comes BEFORE W_glin in dict order
  const float* Wgl  = (const float*)d_in[9];
  float* out = (float*)d_out;

  // Workspace: exactly 256 MiB, no weight buffers (weights converted inline).
  char* ws = (char*)d_ws;
  u16*   a_r = (u16*)(ws);                       // 67108864 B   a_r[c][j][k]  fp16
  u16*   b_r = (u16*)(ws + 67108864);            // 67108864 B   b_r[c][i][k]  fp16
  float* o_f = (float*)(ws + 134217728);         // 134217728 B  o_f[c][i][j]  fp32

  hipLaunchKernelGGL(k1_ln_proj, dim3(2048), dim3(256), 0, stream, pair, mask, ln1w, ln1b, Wp, Wg, a_r, b_r);
  hipLaunchKernelGGL(k2_tri,     dim3(2048), dim3(256), 0, stream, a_r, b_r, o_f);
  hipLaunchKernelGGL(k3_out,     dim3(4096), dim3(256), 0, stream, o_f, pair, ln1w, ln1b, ln2w, ln2b, Wgl, Wo, out);
}